// Round 3
// baseline (185.652 us; speedup 1.0000x reference)
//
#include <hip/hip_runtime.h>

// FeedForwardQuantum: out = relu(cos(x+theta) @ W1 + b1) @ W2 + b2
// x: [B,S,E=8] fp32, W1: [8,32], W2: [32,8]. 524288 tokens of 8 floats.
//
// R3 design: weights in LDS (broadcast ds_read_b128, conflict-free), but
// TOKT=8 tokens/thread so each 64B weight read feeds 136 FMAs (R1: 68,
// R2's s_load path regressed). 256 blocks x 256 thr = 1 block/CU; the
// f-loop is fully unrolled with explicit next-f weight prefetch so the
// ~120cyc LDS latency hides under the 272-cyc FMA block of the current f.

#define TPB 256
#define TOKT 8

__global__ __launch_bounds__(TPB) void ffq_kernel(
    const float4* __restrict__ xv,      // x as float4 pairs: token g -> xv[2g], xv[2g+1]
    const float*  __restrict__ theta,   // [8]
    const float*  __restrict__ w1,      // [8][32] row-major
    const float*  __restrict__ b1,      // [32]
    const float*  __restrict__ w2,      // [32][8] row-major
    const float*  __restrict__ b2,      // [8]
    float4*       __restrict__ outv,    // out as float4 pairs
    int ntok)
{
    // wc[f][0..7]  = W1[0..7][f]  (W1 column f),  wc[f][8..15] = W2[f][0..7]
    __shared__ float wc[32 * 16];
    __shared__ float sb1[32];

    const int tid = threadIdx.x;
    {
        int e = tid >> 5, f = tid & 31;          // w1: tid = e*32+f
        wc[f * 16 + e] = w1[tid];
        int f2 = tid >> 3, e2 = tid & 7;         // w2: tid = f*8+e
        wc[f2 * 16 + 8 + e2] = w2[tid];
    }
    if (tid < 32) sb1[tid] = b1[tid];

    // theta/b2: uniform scalar loads (16 floats, once)
    float th[8], bb2[8];
#pragma unroll
    for (int e = 0; e < 8; ++e) { th[e] = theta[e]; bb2[e] = b2[e]; }

    const int base   = blockIdx.x * TPB + tid;
    const int stride = gridDim.x * TPB;

    // Issue all x loads up front (16 dwordx4 in flight), then cos.
    float4 a[TOKT], c[TOKT];
#pragma unroll
    for (int t = 0; t < TOKT; ++t) {
        int g = base + t * stride;
        if (g < ntok) {
            a[t] = xv[2 * g];
            c[t] = xv[2 * g + 1];
        } else {
            a[t] = make_float4(0.f, 0.f, 0.f, 0.f);
            c[t] = make_float4(0.f, 0.f, 0.f, 0.f);
        }
    }

    __syncthreads();

    float q[TOKT][8];
    float o[TOKT][8];
#pragma unroll
    for (int t = 0; t < TOKT; ++t) {
        q[t][0] = __cosf(a[t].x + th[0]);
        q[t][1] = __cosf(a[t].y + th[1]);
        q[t][2] = __cosf(a[t].z + th[2]);
        q[t][3] = __cosf(a[t].w + th[3]);
        q[t][4] = __cosf(c[t].x + th[4]);
        q[t][5] = __cosf(c[t].y + th[5]);
        q[t][6] = __cosf(c[t].z + th[6]);
        q[t][7] = __cosf(c[t].w + th[7]);
#pragma unroll
        for (int e = 0; e < 8; ++e) o[t][e] = bb2[e];
    }

    // f-loop, fully unrolled, software-pipelined weight reads.
    const float4* wcv = (const float4*)wc;   // wc[f*16] == wcv[f*4]
    float4 wa = wcv[0], wb = wcv[1], va = wcv[2], vb = wcv[3];
    float  bb = sb1[0];

#pragma unroll
    for (int f = 0; f < 32; ++f) {
        float4 nwa, nwb, nva, nvb;
        float  nbb;
        if (f < 31) {                         // folded per unrolled iter
            nwa = wcv[4 * f + 4];
            nwb = wcv[4 * f + 5];
            nva = wcv[4 * f + 6];
            nvb = wcv[4 * f + 7];
            nbb = sb1[f + 1];
        }
#pragma unroll
        for (int t = 0; t < TOKT; ++t) {
            float h = bb;
            h = fmaf(q[t][0], wa.x, h);
            h = fmaf(q[t][1], wa.y, h);
            h = fmaf(q[t][2], wa.z, h);
            h = fmaf(q[t][3], wa.w, h);
            h = fmaf(q[t][4], wb.x, h);
            h = fmaf(q[t][5], wb.y, h);
            h = fmaf(q[t][6], wb.z, h);
            h = fmaf(q[t][7], wb.w, h);
            h = fmaxf(h, 0.0f);
            o[t][0] = fmaf(h, va.x, o[t][0]);
            o[t][1] = fmaf(h, va.y, o[t][1]);
            o[t][2] = fmaf(h, va.z, o[t][2]);
            o[t][3] = fmaf(h, va.w, o[t][3]);
            o[t][4] = fmaf(h, vb.x, o[t][4]);
            o[t][5] = fmaf(h, vb.y, o[t][5]);
            o[t][6] = fmaf(h, vb.z, o[t][6]);
            o[t][7] = fmaf(h, vb.w, o[t][7]);
        }
        wa = nwa; wb = nwb; va = nva; vb = nvb; bb = nbb;
    }

#pragma unroll
    for (int t = 0; t < TOKT; ++t) {
        int g = base + t * stride;
        if (g < ntok) {
            outv[2 * g]     = make_float4(o[t][0], o[t][1], o[t][2], o[t][3]);
            outv[2 * g + 1] = make_float4(o[t][4], o[t][5], o[t][6], o[t][7]);
        }
    }
}

extern "C" void kernel_launch(void* const* d_in, const int* in_sizes, int n_in,
                              void* d_out, int out_size, void* d_ws, size_t ws_size,
                              hipStream_t stream) {
    const float* x     = (const float*)d_in[0];
    const float* theta = (const float*)d_in[1];
    const float* w1    = (const float*)d_in[2];
    const float* b1    = (const float*)d_in[3];
    const float* w2    = (const float*)d_in[4];
    const float* b2    = (const float*)d_in[5];
    float* out = (float*)d_out;

    const int ntok = in_sizes[0] / 8;  // B*S tokens
    const int total_threads = (ntok + TOKT - 1) / TOKT;
    const int grid = (total_threads + TPB - 1) / TPB;

    ffq_kernel<<<grid, TPB, 0, stream>>>(
        (const float4*)x, theta, w1, b1, w2, b2, (float4*)out, ntok);
}

// Round 4
// 84.000 us; speedup vs baseline: 2.2101x; 2.2101x over previous
//
#include <hip/hip_runtime.h>

// FeedForwardQuantum: out = relu(cos(x+theta) @ W1 + b1) @ W2 + b2
// x: [B,S,E=8] fp32, W1: [8,32], W2: [32,8]. 524288 tokens of 8 floats.
//
// R4: scalar (SGPR) weights with a ROLLED f-loop.
//  - R2 failed because full unroll hoisted ~550 uniform loads -> SGPR spill
//    (v_readlane/v_writelane storm). R3 failed on VGPR spill (TOKT=8).
//  - Here: f is a uniform loop counter, so w1[e*32+f]/w2[f*8+e]/b1[f] are
//    uniform addresses -> s_load into ~20 live SGPRs per iteration; FMAs
//    read SGPRs directly. #pragma unroll 2 gives prefetch distance without
//    reviving the spill. No LDS, no __syncthreads.
//  - TOKT=2, 1024 blocks x 256 -> 16 waves/CU: SMEM pipe ~5K cyc/CU under
//    VALU ~10K cyc/SIMD -> VALU-bound at ~4-5 us + memory overlap.

#define TPB 256
#define TOKT 2

__global__ __launch_bounds__(TPB, 4) void ffq_kernel(
    const float4* __restrict__ xv,      // x as float4 pairs: token g -> xv[2g], xv[2g+1]
    const float*  __restrict__ theta,   // [8]
    const float*  __restrict__ w1,      // [8][32] row-major
    const float*  __restrict__ b1,      // [32]
    const float*  __restrict__ w2,      // [32][8] row-major
    const float*  __restrict__ b2,      // [8]
    float4*       __restrict__ outv,    // out as float4 pairs
    int ntok)
{
    const int base   = blockIdx.x * TPB + threadIdx.x;
    const int stride = gridDim.x * TPB;

    // theta/b2: 16 uniform scalar loads, hoisted once.
    float th[8], bb2[8];
#pragma unroll
    for (int e = 0; e < 8; ++e) { th[e] = theta[e]; bb2[e] = b2[e]; }

    float4 a[TOKT], c[TOKT];
#pragma unroll
    for (int t = 0; t < TOKT; ++t) {
        int g = base + t * stride;
        if (g < ntok) {
            a[t] = xv[2 * g];
            c[t] = xv[2 * g + 1];
        } else {
            a[t] = make_float4(0.f, 0.f, 0.f, 0.f);
            c[t] = make_float4(0.f, 0.f, 0.f, 0.f);
        }
    }

    float q[TOKT][8];
    float o[TOKT][8];
#pragma unroll
    for (int t = 0; t < TOKT; ++t) {
        q[t][0] = __cosf(a[t].x + th[0]);
        q[t][1] = __cosf(a[t].y + th[1]);
        q[t][2] = __cosf(a[t].z + th[2]);
        q[t][3] = __cosf(a[t].w + th[3]);
        q[t][4] = __cosf(c[t].x + th[4]);
        q[t][5] = __cosf(c[t].y + th[5]);
        q[t][6] = __cosf(c[t].z + th[6]);
        q[t][7] = __cosf(c[t].w + th[7]);
#pragma unroll
        for (int e = 0; e < 8; ++e) o[t][e] = bb2[e];
    }

    // ROLLED f-loop (unroll 2 only): ~20 live SGPRs of weights per iter.
#pragma unroll 2
    for (int f = 0; f < 32; ++f) {
        const float bb = b1[f];
        float wa[8], wb[8];
#pragma unroll
        for (int e = 0; e < 8; ++e) wa[e] = w1[e * 32 + f];   // W1 column f (uniform)
#pragma unroll
        for (int e = 0; e < 8; ++e) wb[e] = w2[f * 8 + e];    // W2 row f (uniform, contiguous)
#pragma unroll
        for (int t = 0; t < TOKT; ++t) {
            float h = bb;
#pragma unroll
            for (int e = 0; e < 8; ++e) h = fmaf(q[t][e], wa[e], h);
            h = fmaxf(h, 0.0f);
#pragma unroll
            for (int e = 0; e < 8; ++e) o[t][e] = fmaf(h, wb[e], o[t][e]);
        }
    }

#pragma unroll
    for (int t = 0; t < TOKT; ++t) {
        int g = base + t * stride;
        if (g < ntok) {
            outv[2 * g]     = make_float4(o[t][0], o[t][1], o[t][2], o[t][3]);
            outv[2 * g + 1] = make_float4(o[t][4], o[t][5], o[t][6], o[t][7]);
        }
    }
}

extern "C" void kernel_launch(void* const* d_in, const int* in_sizes, int n_in,
                              void* d_out, int out_size, void* d_ws, size_t ws_size,
                              hipStream_t stream) {
    const float* x     = (const float*)d_in[0];
    const float* theta = (const float*)d_in[1];
    const float* w1    = (const float*)d_in[2];
    const float* b1    = (const float*)d_in[3];
    const float* w2    = (const float*)d_in[4];
    const float* b2    = (const float*)d_in[5];
    float* out = (float*)d_out;

    const int ntok = in_sizes[0] / 8;  // B*S tokens
    const int total_threads = (ntok + TOKT - 1) / TOKT;
    const int grid = (total_threads + TPB - 1) / TPB;

    ffq_kernel<<<grid, TPB, 0, stream>>>(
        (const float4*)x, theta, w1, b1, w2, b2, (float4*)out, ntok);
}